// Round 1
// baseline (624.945 us; speedup 1.0000x reference)
//
#include <hip/hip_runtime.h>
#include <hip/hip_bf16.h>

typedef unsigned short u16;
typedef short bf16x8 __attribute__((ext_vector_type(8)));
typedef float f32x4 __attribute__((ext_vector_type(4)));

#define NB 2
#define NS 2048
#define ND 1536
#define NH 8
#define NCQK 128
#define NCV 192
#define NBS 4096
#define NPAD 1408

__device__ __forceinline__ float bf2f(u16 u) {
  unsigned v = ((unsigned)u) << 16;
  return __builtin_bit_cast(float, v);
}
__device__ __forceinline__ u16 f2bf(float f) {
  unsigned u = __builtin_bit_cast(unsigned, f);
  u += 0x7fffu + ((u >> 16) & 1u);
  return (u16)(u >> 16);
}
__device__ __forceinline__ void glds16(const u16* g, u16* l) {
  __builtin_amdgcn_global_load_lds(
      (const __attribute__((address_space(1))) void*)g,
      (__attribute__((address_space(3))) void*)l, 16, 0, 0);
}
__device__ __forceinline__ f32x4 mfma16(bf16x8 a, bf16x8 b, f32x4 c) {
  return __builtin_amdgcn_mfma_f32_16x16x32_bf16(a, b, c, 0, 0, 0);
}

// ---------------- transpose+cast: out[n][k] = bf16(in[k][n]), in fp32 [K][N] ----------------
__global__ void transpose_k(const float* __restrict__ in, u16* __restrict__ out,
                            int K, int N) {
  __shared__ float t[64][65];
  const int n0 = blockIdx.x * 64, k0 = blockIdx.y * 64;
  const int tid = threadIdx.x;
  const int rl = tid >> 4, cl = (tid & 15) * 4;
  for (int p = 0; p < 4; p++) {
    int k = rl + p * 16;
    float4 v = *(const float4*)(in + (size_t)(k0 + k) * N + n0 + cl);
    t[k][cl] = v.x; t[k][cl + 1] = v.y; t[k][cl + 2] = v.z; t[k][cl + 3] = v.w;
  }
  __syncthreads();
  const int rn = tid >> 3, ck = (tid & 7) * 8;
  for (int p = 0; p < 2; p++) {
    int n = rn + p * 32;
    u16 tmp[8];
    for (int j = 0; j < 8; j++) tmp[j] = f2bf(t[ck + j][n]);
    *(uint4*)(out + (size_t)(n0 + n) * K + k0 + ck) = *(uint4*)tmp;
  }
}

// ---------------- rmsnorm of x (fp32) -> h (bf16) ----------------
__global__ void rmsnorm_in_k(const float* __restrict__ x, const float* __restrict__ scale,
                             u16* __restrict__ h) {
  __shared__ float sbuf[4];
  const int row = blockIdx.x, tid = threadIdx.x;
  const float* xr = x + (size_t)row * ND;
  float v[6]; float ss = 0.f;
  for (int i = 0; i < 6; i++) { v[i] = xr[tid + i * 256]; ss += v[i] * v[i]; }
  for (int o = 32; o; o >>= 1) ss += __shfl_xor(ss, o);
  if ((tid & 63) == 0) sbuf[tid >> 6] = ss;
  __syncthreads();
  ss = sbuf[0] + sbuf[1] + sbuf[2] + sbuf[3];
  const float inv = rsqrtf(ss * (1.f / ND) + 1e-6f);
  u16* hr = h + (size_t)row * ND;
  for (int i = 0; i < 6; i++) {
    int c = tid + i * 256;
    hr[c] = f2bf(v[i] * inv * scale[c]);
  }
}

// ---------------- C[M,N] = A[M,K]bf16 @ Bt[N,K]bf16^T ; fp32 or bf16 out ----------------
template <bool F32OUT>
__global__ __launch_bounds__(256, 2)
void gemm_nt(const u16* __restrict__ A, const u16* __restrict__ Bt,
             float* __restrict__ Cf, u16* __restrict__ Cb, int M, int N, int K) {
  __shared__ __align__(16) u16 As[128 * 64];
  __shared__ __align__(16) u16 Bs[128 * 64];
  const int tid = threadIdx.x;
  const int wave = tid >> 6, lane = tid & 63, quad = lane >> 4, l16 = lane & 15;
  const int m0 = blockIdx.y * 128, n0 = blockIdx.x * 128;
  const int mrb = (wave & 1) * 4, nrb = (wave >> 1) * 4;
  f32x4 acc[4][4] = {};
  for (int k0 = 0; k0 < K; k0 += 64) {
    if (k0) __syncthreads();
    for (int i = 0; i < 4; i++) {
      int g = wave * 4 + i;
      int rb = g >> 1, kh = g & 1;
      int row = rb * 16 + l16, kc = kh * 4 + quad;
      glds16(A + (size_t)(m0 + row) * K + k0 + kc * 8, &As[(rb * 8 + kh * 4) * 128]);
      glds16(Bt + (size_t)(n0 + row) * K + k0 + kc * 8, &Bs[(rb * 8 + kh * 4) * 128]);
    }
    __syncthreads();
    for (int kk = 0; kk < 2; kk++) {
      bf16x8 af[4], bfr[4];
      for (int f = 0; f < 4; f++)
        af[f] = *(const bf16x8*)&As[(((mrb + f) * 8 + kk * 4 + quad) * 16 + l16) * 8];
      for (int f = 0; f < 4; f++)
        bfr[f] = *(const bf16x8*)&Bs[(((nrb + f) * 8 + kk * 4 + quad) * 16 + l16) * 8];
      for (int mf = 0; mf < 4; mf++)
        for (int nf = 0; nf < 4; nf++)
          acc[mf][nf] = mfma16(af[mf], bfr[nf], acc[mf][nf]);
    }
  }
  for (int mf = 0; mf < 4; mf++)
    for (int nf = 0; nf < 4; nf++)
      for (int r = 0; r < 4; r++) {
        int m = m0 + (wave & 1) * 64 + mf * 16 + quad * 4 + r;
        int n = n0 + (wave >> 1) * 64 + nf * 16 + l16;
        if (F32OUT) Cf[(size_t)m * N + n] = acc[mf][nf][r];
        else        Cb[(size_t)m * N + n] = f2bf(acc[mf][nf][r]);
      }
}

// ---------------- layernorm + rope on qkv rows (fp32 in, bf16 out) ----------------
__global__ void ln_rope_k(const float* __restrict__ qkv,
                          const float* __restrict__ qs, const float* __restrict__ qo,
                          const float* __restrict__ ks, const float* __restrict__ ko,
                          const float* __restrict__ vs, const float* __restrict__ vo,
                          u16* __restrict__ Qg, u16* __restrict__ Kg, u16* __restrict__ Vg) {
  const int row = blockIdx.x;
  const int b = row >> 11, s = row & (NS - 1);
  const int wave = threadIdx.x >> 6, lane = threadIdx.x & 63;
  const float* base = qkv + (size_t)row * NPAD;
  const float gsp = __expf(logf(8129.f) * ((float)lane * (1.f / 63.f)));
  const float invf = 1.f / ((float)lane + gsp);
  float sn, cs;
  sincosf((float)s * invf, &sn, &cs);

  for (int hh = 0; hh < 2; hh++) {
    const int h = wave * 2 + hh;
    const float* p = base + h * NCQK;
    float x0 = p[lane * 2], x1 = p[lane * 2 + 1];
    float s1 = x0 + x1, s2 = x0 * x0 + x1 * x1;
    for (int o = 32; o; o >>= 1) { s1 += __shfl_xor(s1, o); s2 += __shfl_xor(s2, o); }
    float mean = s1 * (1.f / NCQK);
    float inv = rsqrtf(s2 * (1.f / NCQK) - mean * mean + 1e-5f);
    float y0 = (x0 - mean) * inv * qs[lane * 2] + qo[lane * 2];
    float y1 = (x1 - mean) * inv * qs[lane * 2 + 1] + qo[lane * 2 + 1];
    u16* dst = Qg + (size_t)row * (NH * NCQK) + h * NCQK + lane * 2;
    dst[0] = f2bf(y0 * cs - y1 * sn);
    dst[1] = f2bf(y1 * cs + y0 * sn);
  }
  if (wave == 0) {
    const float* p = base + NH * NCQK;
    float x0 = p[lane * 2], x1 = p[lane * 2 + 1];
    float s1 = x0 + x1, s2 = x0 * x0 + x1 * x1;
    for (int o = 32; o; o >>= 1) { s1 += __shfl_xor(s1, o); s2 += __shfl_xor(s2, o); }
    float mean = s1 * (1.f / NCQK);
    float inv = rsqrtf(s2 * (1.f / NCQK) - mean * mean + 1e-5f);
    float y0 = (x0 - mean) * inv * ks[lane * 2] + ko[lane * 2];
    float y1 = (x1 - mean) * inv * ks[lane * 2 + 1] + ko[lane * 2 + 1];
    u16* dst = Kg + (size_t)row * NCQK + lane * 2;
    dst[0] = f2bf(y0 * cs - y1 * sn);
    dst[1] = f2bf(y1 * cs + y0 * sn);
  }
  if (wave == 1) {
    const float* p = base + NH * NCQK + NCQK;
    float x[3]; float s1 = 0.f, s2 = 0.f;
    for (int i = 0; i < 3; i++) { x[i] = p[lane + i * 64]; s1 += x[i]; s2 += x[i] * x[i]; }
    for (int o = 32; o; o >>= 1) { s1 += __shfl_xor(s1, o); s2 += __shfl_xor(s2, o); }
    float mean = s1 * (1.f / NCV);
    float inv = rsqrtf(s2 * (1.f / NCV) - mean * mean + 1e-5f);
    for (int i = 0; i < 3; i++) {
      int c = lane + i * 64;
      float y = (x[i] - mean) * inv * vs[c] + vo[c];
      Vg[(size_t)(b * NCV + c) * NS + s] = f2bf(y);
    }
  }
}

// ---------------- fused MQA attention, 32-key tiles, double-buffered K/V ----------------
// LDS: Ks 2x8KB + Vs 2x12KB + Ps 4KB = 44KB. Q in registers.
// Per iter: issue stage(t+1) -> QK -> softcap -> bias prefetch(t+1) -> PV -> barrier.
// Loads for t+1 are in flight across the whole compute phase of t (T3 2-phase).
__global__ __launch_bounds__(256, 2)
void attn_k(const u16* __restrict__ Qg, const u16* __restrict__ Kg,
            const u16* __restrict__ Vg, const float* __restrict__ bias,
            u16* __restrict__ Y) {
  __shared__ __align__(16) u16 Ks[2][32 * 128];
  __shared__ __align__(16) u16 Vs[2][192 * 32];
  __shared__ __align__(16) u16 Ps[4][512];
  const int tid = threadIdx.x;
  const int wave = tid >> 6, lane = tid & 63, quad = lane >> 4, l16 = lane & 15;
  const int s0 = blockIdx.x * 64;
  const int h = blockIdx.y, b = blockIdx.z;

  // constants: exp(5*tanh(sv/5)) with sv = sacc*0.08838835 + bias,
  // e2 = 2^(sacc*C1 + bias*C2) = e^{0.4*sv}; P = 2^(C4 + C3/(e2+1)) = e^{5-10/(e2+1)}
  const float C1 = 0.0510069742f;      // 0.08838835 * 0.4 * log2(e)
  const float C2 = 0.5770780163f;      // 0.4 * log2(e)
  const float C3 = -14.4269504089f;    // -10 * log2(e)
  const float C4 = 7.2134752044f;      //   5 * log2(e)

  // Q fragments: global -> regs once (Qs LDS eliminated)
  bf16x8 qa[4];
  {
    const u16* qr = Qg + ((size_t)((b * NS + s0 + wave * 16 + l16) * NH + h)) * NCQK;
#pragma unroll
    for (int kk = 0; kk < 4; kk++)
      qa[kk] = *(const bf16x8*)(qr + (kk * 4 + quad) * 8);
  }

  const u16* Kbase = Kg + (size_t)(b * NS) * NCQK;
  const u16* Vbase = Vg + (size_t)(b * NCV) * NS;
  const float* bp = bias + ((size_t)(b * NH + h) * NS + s0 + wave * 16 + quad * 4) * NS + l16;

  // per-lane staging sources (tile 0); advance by key offset per call
  const u16* ksrc[2];
#pragma unroll
  for (int i = 0; i < 2; i++) {
    int g = wave * 2 + i, kb = g >> 2, kh = g & 3;
    ksrc[i] = Kbase + (size_t)(kb * 16 + l16) * NCQK + (kh * 4 + quad) * 8;
  }
  const u16* vsrc[3];
#pragma unroll
  for (int i = 0; i < 3; i++) {
    int g = wave * 3 + i;
    vsrc[i] = Vbase + (size_t)(g * 16 + l16) * NS + quad * 8;
  }

  auto stage = [&](int buf, int key0) {
#pragma unroll
    for (int i = 0; i < 2; i++) {
      int g = wave * 2 + i;
      glds16(ksrc[i] + (size_t)key0 * NCQK, &Ks[buf][g * 512]);
    }
#pragma unroll
    for (int i = 0; i < 3; i++) {
      int g = wave * 3 + i;
      glds16(vsrc[i] + key0, &Vs[buf][g * 512]);
    }
  };

  float breg[8];
  auto loadB = [&](int key0) {
#pragma unroll
    for (int r = 0; r < 4; r++)
#pragma unroll
      for (int nb = 0; nb < 2; nb++)
        breg[r * 2 + nb] = bp[(size_t)r * NS + key0 + nb * 16];
  };

  const int rbase = quad * 128 + l16 * 8;                          // frag read base (u16)
  const int pwbase = (l16 >> 3) * 128 + quad * 32 + (l16 & 7);     // P write base (u16)

  f32x4 oacc[12] = {};
  float lsum[4] = {0.f, 0.f, 0.f, 0.f};

  stage(0, 0);
  loadB(0);
  __syncthreads();

  for (int kt = 0; kt < NS / 32; kt++) {
    const int cur = kt & 1;
    // issue next tile's loads first: they fly under the whole compute phase
    if (kt + 1 < NS / 32) stage(cur ^ 1, (kt + 1) * 32);

    // QK^T (32 keys x 128 ck)
    f32x4 sacc[2] = {};
#pragma unroll
    for (int kk = 0; kk < 4; kk++)
#pragma unroll
      for (int nb = 0; nb < 2; nb++) {
        bf16x8 kf = *(const bf16x8*)&Ks[cur][(nb * 4 + kk) * 512 + rbase];
        sacc[nb] = mfma16(qa[kk], kf, sacc[nb]);
      }

    // softcap + exp -> Ps (bf16), consume breg
#pragma unroll
    for (int nb = 0; nb < 2; nb++)
#pragma unroll
      for (int r = 0; r < 4; r++) {
        float a = fmaf(sacc[nb][r], C1, breg[r * 2 + nb] * C2);
        float e2;
        asm("v_exp_f32 %0, %1" : "=v"(e2) : "v"(a));
        float u = __builtin_amdgcn_rcpf(e2 + 1.f);
        float a2 = fmaf(u, C3, C4);
        float p;
        asm("v_exp_f32 %0, %1" : "=v"(p) : "v"(a2));
        unsigned pk;
        asm("v_cvt_pk_bf16_f32 %0, %1, %2" : "=v"(pk) : "v"(p), "v"(p));
        lsum[r] += __builtin_bit_cast(float, pk << 16);
        Ps[wave][pwbase + nb * 256 + r * 8] = (u16)pk;
      }

    // prefetch next bias tile (in flight during PV)
    if (kt + 1 < NS / 32) loadB((kt + 1) * 32);

    // PV (K-dim = 32 keys, single A fragment)
    bf16x8 pa = *(const bf16x8*)&Ps[wave][rbase];
#pragma unroll
    for (int nb = 0; nb < 12; nb++) {
      bf16x8 vf = *(const bf16x8*)&Vs[cur][nb * 512 + rbase];
      oacc[nb] = mfma16(pa, vf, oacc[nb]);
    }

    if (kt + 1 < NS / 32) __syncthreads();
  }

  for (int r = 0; r < 4; r++)
    for (int o = 1; o < 16; o <<= 1) lsum[r] += __shfl_xor(lsum[r], o);
  for (int r = 0; r < 4; r++) {
    const float inv = 1.f / lsum[r];
    const int m = s0 + wave * 16 + quad * 4 + r;
    u16* yr = Y + (size_t)(b * NS + m) * ND + h * NCV;
    for (int nb = 0; nb < 12; nb++) yr[nb * 16 + l16] = f2bf(oacc[nb][r] * inv);
  }
}

// ---------------- +bo, rmsnorm, write fp32 out ----------------
__global__ void final_k(const u16* __restrict__ yo, const float* __restrict__ bo,
                        const float* __restrict__ scale, float* __restrict__ out) {
  __shared__ float sbuf[4];
  const int row = blockIdx.x, tid = threadIdx.x;
  const u16* yr = yo + (size_t)row * ND;
  float v[6]; float ss = 0.f;
  for (int i = 0; i < 6; i++) {
    int c = tid + i * 256;
    v[i] = bf2f(yr[c]) + bo[c];
    ss += v[i] * v[i];
  }
  for (int o = 32; o; o >>= 1) ss += __shfl_xor(ss, o);
  if ((tid & 63) == 0) sbuf[tid >> 6] = ss;
  __syncthreads();
  ss = sbuf[0] + sbuf[1] + sbuf[2] + sbuf[3];
  const float inv = rsqrtf(ss * (1.f / ND) + 1e-6f);
  float* orow = out + (size_t)row * ND;
  for (int i = 0; i < 6; i++) {
    int c = tid + i * 256;
    orow[c] = v[i] * inv * scale[c];
  }
}

extern "C" void kernel_launch(void* const* d_in, const int* in_sizes, int n_in,
                              void* d_out, int out_size, void* d_ws, size_t ws_size,
                              hipStream_t stream) {
  const float* x    = (const float*)d_in[0];
  const float* bias = (const float*)d_in[1];
  const float* rin  = (const float*)d_in[2];
  const float* wq   = (const float*)d_in[3];
  const float* wk   = (const float*)d_in[4];
  const float* wv   = (const float*)d_in[5];
  const float* qsc  = (const float*)d_in[6];
  const float* qof  = (const float*)d_in[7];
  const float* ksc  = (const float*)d_in[8];
  const float* kof  = (const float*)d_in[9];
  const float* vsc  = (const float*)d_in[10];
  const float* vof  = (const float*)d_in[11];
  const float* wo   = (const float*)d_in[12];
  const float* bo   = (const float*)d_in[13];
  const float* rout = (const float*)d_in[14];

  char* ws = (char*)d_ws;
  size_t off = 0;
  auto alloc = [&](size_t bytes) -> void* {
    void* p = ws + off;
    off += (bytes + 255) & ~(size_t)255;
    return p;
  };
  u16*   h    = (u16*)alloc((size_t)NBS * ND * 2);
  u16*   wtq  = (u16*)alloc((size_t)NPAD * ND * 2);
  u16*   wto  = (u16*)alloc((size_t)ND * ND * 2);
  float* qkv  = (float*)alloc((size_t)NBS * NPAD * 4);
  u16*   Qb   = (u16*)alloc((size_t)NBS * NH * NCQK * 2);
  u16*   Kb   = (u16*)alloc((size_t)NBS * NCQK * 2);
  u16*   Vtb  = (u16*)alloc((size_t)NB * NCV * NS * 2);
  u16*   Ybf  = (u16*)alloc((size_t)NBS * ND * 2);
  u16*   Yob  = (u16*)alloc((size_t)NBS * ND * 2);

  transpose_k<<<dim3(16, 24), 256, 0, stream>>>(wq, wtq, ND, 1024);
  transpose_k<<<dim3(2, 24), 256, 0, stream>>>(wk, wtq + (size_t)1024 * ND, ND, 128);
  transpose_k<<<dim3(3, 24), 256, 0, stream>>>(wv, wtq + (size_t)1152 * ND, ND, 192);
  transpose_k<<<dim3(24, 24), 256, 0, stream>>>(wo, wto, ND, ND);
  rmsnorm_in_k<<<NBS, 256, 0, stream>>>(x, rin, h);
  gemm_nt<true><<<dim3(NPAD / 128, NBS / 128), 256, 0, stream>>>(h, wtq, qkv, nullptr, NBS, NPAD, ND);
  ln_rope_k<<<NBS, 256, 0, stream>>>(qkv, qsc, qof, ksc, kof, vsc, vof, Qb, Kb, Vtb);
  attn_k<<<dim3(NS / 64, NH, NB), 256, 0, stream>>>(Qb, Kb, Vtb, bias, Ybf);
  gemm_nt<false><<<dim3(ND / 128, NBS / 128), 256, 0, stream>>>(Ybf, wto, nullptr, Yob, NBS, ND, ND);
  final_k<<<NBS, 256, 0, stream>>>(Yob, bo, rout, (float*)d_out);
}

// Round 2
// 590.061 us; speedup vs baseline: 1.0591x; 1.0591x over previous
//
#include <hip/hip_runtime.h>
#include <hip/hip_bf16.h>

typedef unsigned short u16;
typedef short bf16x8 __attribute__((ext_vector_type(8)));
typedef float f32x4 __attribute__((ext_vector_type(4)));

#define NB 2
#define NS 2048
#define ND 1536
#define NH 8
#define NCQK 128
#define NCV 192
#define NBS 4096
#define NPAD 1408

__device__ __forceinline__ float bf2f(u16 u) {
  unsigned v = ((unsigned)u) << 16;
  return __builtin_bit_cast(float, v);
}
__device__ __forceinline__ u16 f2bf(float f) {
  unsigned u = __builtin_bit_cast(unsigned, f);
  u += 0x7fffu + ((u >> 16) & 1u);
  return (u16)(u >> 16);
}
__device__ __forceinline__ void glds16(const u16* g, u16* l) {
  __builtin_amdgcn_global_load_lds(
      (const __attribute__((address_space(1))) void*)g,
      (__attribute__((address_space(3))) void*)l, 16, 0, 0);
}
__device__ __forceinline__ f32x4 mfma16(bf16x8 a, bf16x8 b, f32x4 c) {
  return __builtin_amdgcn_mfma_f32_16x16x32_bf16(a, b, c, 0, 0, 0);
}

// ---------------- transpose+cast: out[n][k] = bf16(in[k][n]), in fp32 [K][N] ----------------
__global__ void transpose_k(const float* __restrict__ in, u16* __restrict__ out,
                            int K, int N) {
  __shared__ float t[64][65];
  const int n0 = blockIdx.x * 64, k0 = blockIdx.y * 64;
  const int tid = threadIdx.x;
  const int rl = tid >> 4, cl = (tid & 15) * 4;
  for (int p = 0; p < 4; p++) {
    int k = rl + p * 16;
    float4 v = *(const float4*)(in + (size_t)(k0 + k) * N + n0 + cl);
    t[k][cl] = v.x; t[k][cl + 1] = v.y; t[k][cl + 2] = v.z; t[k][cl + 3] = v.w;
  }
  __syncthreads();
  const int rn = tid >> 3, ck = (tid & 7) * 8;
  for (int p = 0; p < 2; p++) {
    int n = rn + p * 32;
    u16 tmp[8];
    for (int j = 0; j < 8; j++) tmp[j] = f2bf(t[ck + j][n]);
    *(uint4*)(out + (size_t)(n0 + n) * K + k0 + ck) = *(uint4*)tmp;
  }
}

// ---------------- rmsnorm of x (fp32) -> h (bf16) ----------------
__global__ void rmsnorm_in_k(const float* __restrict__ x, const float* __restrict__ scale,
                             u16* __restrict__ h) {
  __shared__ float sbuf[4];
  const int row = blockIdx.x, tid = threadIdx.x;
  const float* xr = x + (size_t)row * ND;
  float v[6]; float ss = 0.f;
  for (int i = 0; i < 6; i++) { v[i] = xr[tid + i * 256]; ss += v[i] * v[i]; }
  for (int o = 32; o; o >>= 1) ss += __shfl_xor(ss, o);
  if ((tid & 63) == 0) sbuf[tid >> 6] = ss;
  __syncthreads();
  ss = sbuf[0] + sbuf[1] + sbuf[2] + sbuf[3];
  const float inv = rsqrtf(ss * (1.f / ND) + 1e-6f);
  u16* hr = h + (size_t)row * ND;
  for (int i = 0; i < 6; i++) {
    int c = tid + i * 256;
    hr[c] = f2bf(v[i] * inv * scale[c]);
  }
}

// ---------------- C[M,N] = A[M,K]bf16 @ Bt[N,K]bf16^T ; fp32 or bf16 out ----------------
template <bool F32OUT>
__global__ __launch_bounds__(256, 2)
void gemm_nt(const u16* __restrict__ A, const u16* __restrict__ Bt,
             float* __restrict__ Cf, u16* __restrict__ Cb, int M, int N, int K) {
  __shared__ __align__(16) u16 As[128 * 64];
  __shared__ __align__(16) u16 Bs[128 * 64];
  const int tid = threadIdx.x;
  const int wave = tid >> 6, lane = tid & 63, quad = lane >> 4, l16 = lane & 15;
  const int m0 = blockIdx.y * 128, n0 = blockIdx.x * 128;
  const int mrb = (wave & 1) * 4, nrb = (wave >> 1) * 4;
  f32x4 acc[4][4] = {};
  for (int k0 = 0; k0 < K; k0 += 64) {
    if (k0) __syncthreads();
    for (int i = 0; i < 4; i++) {
      int g = wave * 4 + i;
      int rb = g >> 1, kh = g & 1;
      int row = rb * 16 + l16, kc = kh * 4 + quad;
      glds16(A + (size_t)(m0 + row) * K + k0 + kc * 8, &As[(rb * 8 + kh * 4) * 128]);
      glds16(Bt + (size_t)(n0 + row) * K + k0 + kc * 8, &Bs[(rb * 8 + kh * 4) * 128]);
    }
    __syncthreads();
    for (int kk = 0; kk < 2; kk++) {
      bf16x8 af[4], bfr[4];
      for (int f = 0; f < 4; f++)
        af[f] = *(const bf16x8*)&As[(((mrb + f) * 8 + kk * 4 + quad) * 16 + l16) * 8];
      for (int f = 0; f < 4; f++)
        bfr[f] = *(const bf16x8*)&Bs[(((nrb + f) * 8 + kk * 4 + quad) * 16 + l16) * 8];
      for (int mf = 0; mf < 4; mf++)
        for (int nf = 0; nf < 4; nf++)
          acc[mf][nf] = mfma16(af[mf], bfr[nf], acc[mf][nf]);
    }
  }
  for (int mf = 0; mf < 4; mf++)
    for (int nf = 0; nf < 4; nf++)
      for (int r = 0; r < 4; r++) {
        int m = m0 + (wave & 1) * 64 + mf * 16 + quad * 4 + r;
        int n = n0 + (wave >> 1) * 64 + nf * 16 + l16;
        if (F32OUT) Cf[(size_t)m * N + n] = acc[mf][nf][r];
        else        Cb[(size_t)m * N + n] = f2bf(acc[mf][nf][r]);
      }
}

// ---------------- layernorm + rope on qkv rows (fp32 in, bf16 out) ----------------
__global__ void ln_rope_k(const float* __restrict__ qkv,
                          const float* __restrict__ qs, const float* __restrict__ qo,
                          const float* __restrict__ ks, const float* __restrict__ ko,
                          const float* __restrict__ vs, const float* __restrict__ vo,
                          u16* __restrict__ Qg, u16* __restrict__ Kg, u16* __restrict__ Vg) {
  const int row = blockIdx.x;
  const int b = row >> 11, s = row & (NS - 1);
  const int wave = threadIdx.x >> 6, lane = threadIdx.x & 63;
  const float* base = qkv + (size_t)row * NPAD;
  const float gsp = __expf(logf(8129.f) * ((float)lane * (1.f / 63.f)));
  const float invf = 1.f / ((float)lane + gsp);
  float sn, cs;
  sincosf((float)s * invf, &sn, &cs);

  for (int hh = 0; hh < 2; hh++) {
    const int h = wave * 2 + hh;
    const float* p = base + h * NCQK;
    float x0 = p[lane * 2], x1 = p[lane * 2 + 1];
    float s1 = x0 + x1, s2 = x0 * x0 + x1 * x1;
    for (int o = 32; o; o >>= 1) { s1 += __shfl_xor(s1, o); s2 += __shfl_xor(s2, o); }
    float mean = s1 * (1.f / NCQK);
    float inv = rsqrtf(s2 * (1.f / NCQK) - mean * mean + 1e-5f);
    float y0 = (x0 - mean) * inv * qs[lane * 2] + qo[lane * 2];
    float y1 = (x1 - mean) * inv * qs[lane * 2 + 1] + qo[lane * 2 + 1];
    u16* dst = Qg + (size_t)row * (NH * NCQK) + h * NCQK + lane * 2;
    dst[0] = f2bf(y0 * cs - y1 * sn);
    dst[1] = f2bf(y1 * cs + y0 * sn);
  }
  if (wave == 0) {
    const float* p = base + NH * NCQK;
    float x0 = p[lane * 2], x1 = p[lane * 2 + 1];
    float s1 = x0 + x1, s2 = x0 * x0 + x1 * x1;
    for (int o = 32; o; o >>= 1) { s1 += __shfl_xor(s1, o); s2 += __shfl_xor(s2, o); }
    float mean = s1 * (1.f / NCQK);
    float inv = rsqrtf(s2 * (1.f / NCQK) - mean * mean + 1e-5f);
    float y0 = (x0 - mean) * inv * ks[lane * 2] + ko[lane * 2];
    float y1 = (x1 - mean) * inv * ks[lane * 2 + 1] + ko[lane * 2 + 1];
    u16* dst = Kg + (size_t)row * NCQK + lane * 2;
    dst[0] = f2bf(y0 * cs - y1 * sn);
    dst[1] = f2bf(y1 * cs + y0 * sn);
  }
  if (wave == 1) {
    const float* p = base + NH * NCQK + NCQK;
    float x[3]; float s1 = 0.f, s2 = 0.f;
    for (int i = 0; i < 3; i++) { x[i] = p[lane + i * 64]; s1 += x[i]; s2 += x[i] * x[i]; }
    for (int o = 32; o; o >>= 1) { s1 += __shfl_xor(s1, o); s2 += __shfl_xor(s2, o); }
    float mean = s1 * (1.f / NCV);
    float inv = rsqrtf(s2 * (1.f / NCV) - mean * mean + 1e-5f);
    for (int i = 0; i < 3; i++) {
      int c = lane + i * 64;
      float y = (x[i] - mean) * inv * vs[c] + vo[c];
      Vg[(size_t)(b * NCV + c) * NS + s] = f2bf(y);
    }
  }
}

// ---------------- fused MQA attention: 64-key tiles (round-0 structure),
// cheap softcap (exp2/rcp/cvt_pk), Q in regs, LDS 48KB -> 3 blocks/CU ----------------
__global__ __launch_bounds__(256, 3)
void attn_k(const u16* __restrict__ Qg, const u16* __restrict__ Kg,
            const u16* __restrict__ Vg, const float* __restrict__ bias,
            u16* __restrict__ Y) {
  __shared__ __align__(16) u16 Ks[64 * 128];   // 16KB
  __shared__ __align__(16) u16 Vs[192 * 64];   // 24KB
  __shared__ __align__(16) u16 Ps[64 * 64];    // 8KB
  const int tid = threadIdx.x;
  const int wave = tid >> 6, lane = tid & 63, quad = lane >> 4, l16 = lane & 15;
  const int s0 = blockIdx.x * 64;
  const int h = blockIdx.y, b = blockIdx.z;

  // P = exp(5*tanh(sv/5)), sv = sacc*0.08838835 + bias.
  // e2 = 2^(sacc*C1 + bias*C2) = e^{0.4 sv}; P = 2^(C4 + C3/(e2+1)) = e^{5 - 10/(e2+1)}
  const float C1 = 0.0510069742f;      // 0.08838835 * 0.4 * log2(e)
  const float C2 = 0.5770780163f;      // 0.4 * log2(e)
  const float C3 = -14.4269504089f;    // -10 * log2(e)
  const float C4 = 7.2134752044f;      //   5 * log2(e)

  // Q fragments straight to registers
  bf16x8 qa[4];
  {
    const u16* qr = Qg + ((size_t)((b * NS + s0 + wave * 16 + l16) * NH + h)) * NCQK;
#pragma unroll
    for (int kk = 0; kk < 4; kk++)
      qa[kk] = *(const bf16x8*)(qr + (kk * 4 + quad) * 8);
  }

  const u16* Kbase = Kg + (size_t)(b * NS) * NCQK;
  const u16* Vbase = Vg + (size_t)(b * NCV) * NS;
  const float* brow = bias + ((size_t)(b * NH + h) * NS + s0 + wave * 16) * NS;

  // stage K/V tile 0
#pragma unroll
  for (int i = 0; i < 4; i++)
    glds16(Kbase + (size_t)(wave * 16 + l16) * NCQK + (i * 4 + quad) * 8,
           &Ks[(wave * 16 + i * 4) * 128]);
#pragma unroll
  for (int i = 0; i < 6; i++) {
    int g = wave * 6 + i, cb = g >> 1, kh = g & 1;
    glds16(Vbase + (size_t)(cb * 16 + l16) * NS + (kh * 4 + quad) * 8,
           &Vs[(cb * 8 + kh * 4) * 128]);
  }
  // bias tile 0 into registers
  float breg[16];
#pragma unroll
  for (int nb = 0; nb < 4; nb++)
#pragma unroll
    for (int r = 0; r < 4; r++)
      breg[nb * 4 + r] = brow[(size_t)(quad * 4 + r) * NS + nb * 16 + l16];
  __syncthreads();

  f32x4 oacc[12] = {};
  float lsum[4] = {0.f, 0.f, 0.f, 0.f};

  for (int kt = 0; kt < NS / 64; kt++) {
    // QK^T
    f32x4 sacc[4] = {};
    __builtin_amdgcn_s_setprio(1);
#pragma unroll
    for (int kk = 0; kk < 4; kk++)
#pragma unroll
      for (int nb = 0; nb < 4; nb++) {
        bf16x8 kf = *(const bf16x8*)&Ks[((nb * 16 + kk * 4 + quad) * 16 + l16) * 8];
        sacc[nb] = mfma16(qa[kk], kf, sacc[nb]);
      }
    __builtin_amdgcn_s_setprio(0);

    // softcap + exp -> Ps (bf16); consumes breg
#pragma unroll
    for (int nb = 0; nb < 4; nb++) {
      const int key_l = nb * 16 + l16;
#pragma unroll
      for (int r = 0; r < 4; r++) {
        const int qrow = quad * 4 + r;
        float a = fmaf(sacc[nb][r], C1, breg[nb * 4 + r] * C2);
        float e2;
        asm("v_exp_f32 %0, %1" : "=v"(e2) : "v"(a));
        float u = __builtin_amdgcn_rcpf(e2 + 1.f);
        float a2 = fmaf(u, C3, C4);
        float p;
        asm("v_exp_f32 %0, %1" : "=v"(p) : "v"(a2));
        unsigned pk;
        asm("v_cvt_pk_bf16_f32 %0, %1, %2" : "=v"(pk) : "v"(p), "v"(p));
        lsum[r] += __builtin_bit_cast(float, pk << 16);
        Ps[((wave * 8 + (key_l >> 3)) * 16 + qrow) * 8 + (key_l & 7)] = (u16)pk;
      }
    }

    // prefetch next bias tile now: PV's MFMAs cover the HBM latency
    if (kt + 1 < NS / 64) {
      const int key0 = (kt + 1) * 64;
#pragma unroll
      for (int nb = 0; nb < 4; nb++)
#pragma unroll
        for (int r = 0; r < 4; r++)
          breg[nb * 4 + r] = brow[(size_t)(quad * 4 + r) * NS + key0 + nb * 16 + l16];
    }

    // PV
    __builtin_amdgcn_s_setprio(1);
#pragma unroll
    for (int kk = 0; kk < 2; kk++) {
      bf16x8 pa = *(const bf16x8*)&Ps[((wave * 8 + kk * 4 + quad) * 16 + l16) * 8];
#pragma unroll
      for (int nb = 0; nb < 12; nb++) {
        bf16x8 vf = *(const bf16x8*)&Vs[((nb * 8 + kk * 4 + quad) * 16 + l16) * 8];
        oacc[nb] = mfma16(pa, vf, oacc[nb]);
      }
    }
    __builtin_amdgcn_s_setprio(0);

    // stage next K/V tile
    if (kt + 1 < NS / 64) {
      const int key0 = (kt + 1) * 64;
      __syncthreads();
#pragma unroll
      for (int i = 0; i < 4; i++)
        glds16(Kbase + (size_t)(key0 + wave * 16 + l16) * NCQK + (i * 4 + quad) * 8,
               &Ks[(wave * 16 + i * 4) * 128]);
#pragma unroll
      for (int i = 0; i < 6; i++) {
        int g = wave * 6 + i, cb = g >> 1, kh = g & 1;
        glds16(Vbase + (size_t)(cb * 16 + l16) * NS + key0 + (kh * 4 + quad) * 8,
               &Vs[(cb * 8 + kh * 4) * 128]);
      }
      __syncthreads();
    }
  }

  for (int r = 0; r < 4; r++)
    for (int o = 1; o < 16; o <<= 1) lsum[r] += __shfl_xor(lsum[r], o);
  for (int r = 0; r < 4; r++) {
    const float inv = 1.f / lsum[r];
    const int m = s0 + wave * 16 + quad * 4 + r;
    u16* yr = Y + (size_t)(b * NS + m) * ND + h * NCV;
    for (int nb = 0; nb < 12; nb++) yr[nb * 16 + l16] = f2bf(oacc[nb][r] * inv);
  }
}

// ---------------- +bo, rmsnorm, write fp32 out ----------------
__global__ void final_k(const u16* __restrict__ yo, const float* __restrict__ bo,
                        const float* __restrict__ scale, float* __restrict__ out) {
  __shared__ float sbuf[4];
  const int row = blockIdx.x, tid = threadIdx.x;
  const u16* yr = yo + (size_t)row * ND;
  float v[6]; float ss = 0.f;
  for (int i = 0; i < 6; i++) {
    int c = tid + i * 256;
    v[i] = bf2f(yr[c]) + bo[c];
    ss += v[i] * v[i];
  }
  for (int o = 32; o; o >>= 1) ss += __shfl_xor(ss, o);
  if ((tid & 63) == 0) sbuf[tid >> 6] = ss;
  __syncthreads();
  ss = sbuf[0] + sbuf[1] + sbuf[2] + sbuf[3];
  const float inv = rsqrtf(ss * (1.f / ND) + 1e-6f);
  float* orow = out + (size_t)row * ND;
  for (int i = 0; i < 6; i++) {
    int c = tid + i * 256;
    orow[c] = v[i] * inv * scale[c];
  }
}

extern "C" void kernel_launch(void* const* d_in, const int* in_sizes, int n_in,
                              void* d_out, int out_size, void* d_ws, size_t ws_size,
                              hipStream_t stream) {
  const float* x    = (const float*)d_in[0];
  const float* bias = (const float*)d_in[1];
  const float* rin  = (const float*)d_in[2];
  const float* wq   = (const float*)d_in[3];
  const float* wk   = (const float*)d_in[4];
  const float* wv   = (const float*)d_in[5];
  const float* qsc  = (const float*)d_in[6];
  const float* qof  = (const float*)d_in[7];
  const float* ksc  = (const float*)d_in[8];
  const float* kof  = (const float*)d_in[9];
  const float* vsc  = (const float*)d_in[10];
  const float* vof  = (const float*)d_in[11];
  const float* wo   = (const float*)d_in[12];
  const float* bo   = (const float*)d_in[13];
  const float* rout = (const float*)d_in[14];

  char* ws = (char*)d_ws;
  size_t off = 0;
  auto alloc = [&](size_t bytes) -> void* {
    void* p = ws + off;
    off += (bytes + 255) & ~(size_t)255;
    return p;
  };
  u16*   h    = (u16*)alloc((size_t)NBS * ND * 2);
  u16*   wtq  = (u16*)alloc((size_t)NPAD * ND * 2);
  u16*   wto  = (u16*)alloc((size_t)ND * ND * 2);
  float* qkv  = (float*)alloc((size_t)NBS * NPAD * 4);
  u16*   Qb   = (u16*)alloc((size_t)NBS * NH * NCQK * 2);
  u16*   Kb   = (u16*)alloc((size_t)NBS * NCQK * 2);
  u16*   Vtb  = (u16*)alloc((size_t)NB * NCV * NS * 2);
  u16*   Ybf  = (u16*)alloc((size_t)NBS * ND * 2);
  u16*   Yob  = (u16*)alloc((size_t)NBS * ND * 2);

  transpose_k<<<dim3(16, 24), 256, 0, stream>>>(wq, wtq, ND, 1024);
  transpose_k<<<dim3(2, 24), 256, 0, stream>>>(wk, wtq + (size_t)1024 * ND, ND, 128);
  transpose_k<<<dim3(3, 24), 256, 0, stream>>>(wv, wtq + (size_t)1152 * ND, ND, 192);
  transpose_k<<<dim3(24, 24), 256, 0, stream>>>(wo, wto, ND, ND);
  rmsnorm_in_k<<<NBS, 256, 0, stream>>>(x, rin, h);
  gemm_nt<true><<<dim3(NPAD / 128, NBS / 128), 256, 0, stream>>>(h, wtq, qkv, nullptr, NBS, NPAD, ND);
  ln_rope_k<<<NBS, 256, 0, stream>>>(qkv, qsc, qof, ksc, kof, vsc, vof, Qb, Kb, Vtb);
  attn_k<<<dim3(NS / 64, NH, NB), 256, 0, stream>>>(Qb, Kb, Vtb, bias, Ybf);
  gemm_nt<false><<<dim3(ND / 128, NBS / 128), 256, 0, stream>>>(Ybf, wto, nullptr, Yob, NBS, ND, ND);
  final_k<<<NBS, 256, 0, stream>>>(Yob, bo, rout, (float*)d_out);
}

// Round 4
// 585.910 us; speedup vs baseline: 1.0666x; 1.0071x over previous
//
#include <hip/hip_runtime.h>
#include <hip/hip_bf16.h>

typedef unsigned short u16;
typedef short bf16x8 __attribute__((ext_vector_type(8)));
typedef float f32x4 __attribute__((ext_vector_type(4)));

#define NB 2
#define NS 2048
#define ND 1536
#define NH 8
#define NCQK 128
#define NCV 192
#define NBS 4096
#define NPAD 1408

__device__ __forceinline__ float bf2f(u16 u) {
  unsigned v = ((unsigned)u) << 16;
  return __builtin_bit_cast(float, v);
}
__device__ __forceinline__ u16 f2bf(float f) {
  unsigned u = __builtin_bit_cast(unsigned, f);
  u += 0x7fffu + ((u >> 16) & 1u);
  return (u16)(u >> 16);
}
__device__ __forceinline__ void glds16(const u16* g, u16* l) {
  __builtin_amdgcn_global_load_lds(
      (const __attribute__((address_space(1))) void*)g,
      (__attribute__((address_space(3))) void*)l, 16, 0, 0);
}
__device__ __forceinline__ f32x4 mfma16(bf16x8 a, bf16x8 b, f32x4 c) {
  return __builtin_amdgcn_mfma_f32_16x16x32_bf16(a, b, c, 0, 0, 0);
}

// ---------------- transpose+cast: out[n][k] = bf16(in[k][n]), in fp32 [K][N] ----------------
__global__ void transpose_k(const float* __restrict__ in, u16* __restrict__ out,
                            int K, int N) {
  __shared__ float t[64][65];
  const int n0 = blockIdx.x * 64, k0 = blockIdx.y * 64;
  const int tid = threadIdx.x;
  const int rl = tid >> 4, cl = (tid & 15) * 4;
  for (int p = 0; p < 4; p++) {
    int k = rl + p * 16;
    float4 v = *(const float4*)(in + (size_t)(k0 + k) * N + n0 + cl);
    t[k][cl] = v.x; t[k][cl + 1] = v.y; t[k][cl + 2] = v.z; t[k][cl + 3] = v.w;
  }
  __syncthreads();
  const int rn = tid >> 3, ck = (tid & 7) * 8;
  for (int p = 0; p < 2; p++) {
    int n = rn + p * 32;
    u16 tmp[8];
    for (int j = 0; j < 8; j++) tmp[j] = f2bf(t[ck + j][n]);
    *(uint4*)(out + (size_t)(n0 + n) * K + k0 + ck) = *(uint4*)tmp;
  }
}

// ---------------- rmsnorm of x (fp32) -> h (bf16) ----------------
__global__ void rmsnorm_in_k(const float* __restrict__ x, const float* __restrict__ scale,
                             u16* __restrict__ h) {
  __shared__ float sbuf[4];
  const int row = blockIdx.x, tid = threadIdx.x;
  const float* xr = x + (size_t)row * ND;
  float v[6]; float ss = 0.f;
  for (int i = 0; i < 6; i++) { v[i] = xr[tid + i * 256]; ss += v[i] * v[i]; }
  for (int o = 32; o; o >>= 1) ss += __shfl_xor(ss, o);
  if ((tid & 63) == 0) sbuf[tid >> 6] = ss;
  __syncthreads();
  ss = sbuf[0] + sbuf[1] + sbuf[2] + sbuf[3];
  const float inv = rsqrtf(ss * (1.f / ND) + 1e-6f);
  u16* hr = h + (size_t)row * ND;
  for (int i = 0; i < 6; i++) {
    int c = tid + i * 256;
    hr[c] = f2bf(v[i] * inv * scale[c]);
  }
}

// ---------------- C[M,N] = A[M,K]bf16 @ Bt[N,K]bf16^T ; fp32 or bf16 out ----------------
template <bool F32OUT>
__global__ __launch_bounds__(256, 2)
void gemm_nt(const u16* __restrict__ A, const u16* __restrict__ Bt,
             float* __restrict__ Cf, u16* __restrict__ Cb, int M, int N, int K) {
  __shared__ __align__(16) u16 As[128 * 64];
  __shared__ __align__(16) u16 Bs[128 * 64];
  const int tid = threadIdx.x;
  const int wave = tid >> 6, lane = tid & 63, quad = lane >> 4, l16 = lane & 15;
  const int m0 = blockIdx.y * 128, n0 = blockIdx.x * 128;
  const int mrb = (wave & 1) * 4, nrb = (wave >> 1) * 4;
  f32x4 acc[4][4] = {};
  for (int k0 = 0; k0 < K; k0 += 64) {
    if (k0) __syncthreads();
    for (int i = 0; i < 4; i++) {
      int g = wave * 4 + i;
      int rb = g >> 1, kh = g & 1;
      int row = rb * 16 + l16, kc = kh * 4 + quad;
      glds16(A + (size_t)(m0 + row) * K + k0 + kc * 8, &As[(rb * 8 + kh * 4) * 128]);
      glds16(Bt + (size_t)(n0 + row) * K + k0 + kc * 8, &Bs[(rb * 8 + kh * 4) * 128]);
    }
    __syncthreads();
    for (int kk = 0; kk < 2; kk++) {
      bf16x8 af[4], bfr[4];
      for (int f = 0; f < 4; f++)
        af[f] = *(const bf16x8*)&As[(((mrb + f) * 8 + kk * 4 + quad) * 16 + l16) * 8];
      for (int f = 0; f < 4; f++)
        bfr[f] = *(const bf16x8*)&Bs[(((nrb + f) * 8 + kk * 4 + quad) * 16 + l16) * 8];
      for (int mf = 0; mf < 4; mf++)
        for (int nf = 0; nf < 4; nf++)
          acc[mf][nf] = mfma16(af[mf], bfr[nf], acc[mf][nf]);
    }
  }
  for (int mf = 0; mf < 4; mf++)
    for (int nf = 0; nf < 4; nf++)
      for (int r = 0; r < 4; r++) {
        int m = m0 + (wave & 1) * 64 + mf * 16 + quad * 4 + r;
        int n = n0 + (wave >> 1) * 64 + nf * 16 + l16;
        if (F32OUT) Cf[(size_t)m * N + n] = acc[mf][nf][r];
        else        Cb[(size_t)m * N + n] = f2bf(acc[mf][nf][r]);
      }
}

// ---------------- layernorm + rope on qkv rows (fp32 in, bf16 out) ----------------
__global__ void ln_rope_k(const float* __restrict__ qkv,
                          const float* __restrict__ qs, const float* __restrict__ qo,
                          const float* __restrict__ ks, const float* __restrict__ ko,
                          const float* __restrict__ vs, const float* __restrict__ vo,
                          u16* __restrict__ Qg, u16* __restrict__ Kg, u16* __restrict__ Vg) {
  const int row = blockIdx.x;
  const int b = row >> 11, s = row & (NS - 1);
  const int wave = threadIdx.x >> 6, lane = threadIdx.x & 63;
  const float* base = qkv + (size_t)row * NPAD;
  const float gsp = __expf(logf(8129.f) * ((float)lane * (1.f / 63.f)));
  const float invf = 1.f / ((float)lane + gsp);
  float sn, cs;
  sincosf((float)s * invf, &sn, &cs);

  for (int hh = 0; hh < 2; hh++) {
    const int h = wave * 2 + hh;
    const float* p = base + h * NCQK;
    float x0 = p[lane * 2], x1 = p[lane * 2 + 1];
    float s1 = x0 + x1, s2 = x0 * x0 + x1 * x1;
    for (int o = 32; o; o >>= 1) { s1 += __shfl_xor(s1, o); s2 += __shfl_xor(s2, o); }
    float mean = s1 * (1.f / NCQK);
    float inv = rsqrtf(s2 * (1.f / NCQK) - mean * mean + 1e-5f);
    float y0 = (x0 - mean) * inv * qs[lane * 2] + qo[lane * 2];
    float y1 = (x1 - mean) * inv * qs[lane * 2 + 1] + qo[lane * 2 + 1];
    u16* dst = Qg + (size_t)row * (NH * NCQK) + h * NCQK + lane * 2;
    dst[0] = f2bf(y0 * cs - y1 * sn);
    dst[1] = f2bf(y1 * cs + y0 * sn);
  }
  if (wave == 0) {
    const float* p = base + NH * NCQK;
    float x0 = p[lane * 2], x1 = p[lane * 2 + 1];
    float s1 = x0 + x1, s2 = x0 * x0 + x1 * x1;
    for (int o = 32; o; o >>= 1) { s1 += __shfl_xor(s1, o); s2 += __shfl_xor(s2, o); }
    float mean = s1 * (1.f / NCQK);
    float inv = rsqrtf(s2 * (1.f / NCQK) - mean * mean + 1e-5f);
    float y0 = (x0 - mean) * inv * ks[lane * 2] + ko[lane * 2];
    float y1 = (x1 - mean) * inv * ks[lane * 2 + 1] + ko[lane * 2 + 1];
    u16* dst = Kg + (size_t)row * NCQK + lane * 2;
    dst[0] = f2bf(y0 * cs - y1 * sn);
    dst[1] = f2bf(y1 * cs + y0 * sn);
  }
  if (wave == 1) {
    const float* p = base + NH * NCQK + NCQK;
    float x[3]; float s1 = 0.f, s2 = 0.f;
    for (int i = 0; i < 3; i++) { x[i] = p[lane + i * 64]; s1 += x[i]; s2 += x[i] * x[i]; }
    for (int o = 32; o; o >>= 1) { s1 += __shfl_xor(s1, o); s2 += __shfl_xor(s2, o); }
    float mean = s1 * (1.f / NCV);
    float inv = rsqrtf(s2 * (1.f / NCV) - mean * mean + 1e-5f);
    for (int i = 0; i < 3; i++) {
      int c = lane + i * 64;
      float y = (x[i] - mean) * inv * vs[c] + vo[c];
      Vg[(size_t)(b * NCV + c) * NS + s] = f2bf(y);
    }
  }
}

// ---------------- fused MQA attention ----------------
// 64 q-rows x 64-key tiles; 4 waves = 2 pairs. Pair p handles keys [p*32, p*32+32)
// of each tile for ALL 64 rows; each wave owns 32 rows (2 M-frags sharing every
// kf/vf LDS read). LDS read traffic per row ~halved vs 16-rows/wave. Partial O and
// softmax sums combined in an f32 epilogue through reused smem (exactly 48KB).
__global__ __launch_bounds__(256, 2)
void attn_k(const u16* __restrict__ Qg, const u16* __restrict__ Kg,
            const u16* __restrict__ Vg, const float* __restrict__ bias,
            u16* __restrict__ Y) {
  __shared__ __align__(16) u16 smem[24576];  // Ks[0,8192) Vs[8192,20480) Ps[20480,24576)
  __shared__ float lbuf[64];
  u16* Ks = smem;
  u16* Vs = smem + 8192;
  u16* Ps = smem + 20480;
  const int tid = threadIdx.x;
  const int wave = tid >> 6, lane = tid & 63, quad = lane >> 4, l16 = lane & 15;
  const int pair = wave >> 1, rw = wave & 1;   // pair: key half; rw: row half
  const int s0 = blockIdx.x * 64;
  const int h = blockIdx.y, b = blockIdx.z;

  // P = exp(5*tanh(sv/5)), sv = sacc*0.08838835 + bias.
  // e2 = 2^(sacc*C1 + bias*C2) = e^{0.4 sv}; P = 2^(C4 + C3/(e2+1)) = e^{5 - 10/(e2+1)}
  const float C1 = 0.0510069742f;
  const float C2 = 0.5770780163f;
  const float C3 = -14.4269504089f;
  const float C4 = 7.2134752044f;

  // Q: 32 rows/wave, 2 m-frags, straight to registers
  bf16x8 qa[2][4];
#pragma unroll
  for (int mf = 0; mf < 2; mf++) {
    const u16* qr = Qg + ((size_t)((b * NS + s0 + rw * 32 + mf * 16 + l16) * NH + h)) * NCQK;
#pragma unroll
    for (int kk = 0; kk < 4; kk++)
      qa[mf][kk] = *(const bf16x8*)(qr + (kk * 4 + quad) * 8);
  }

  const u16* Kbase = Kg + (size_t)(b * NS) * NCQK;
  const u16* Vbase = Vg + (size_t)(b * NCV) * NS;
  // bias rows: s0 + rw*32 + mf*16 + quad*4 + r ; cols: kt*64 + pair*32 + nb*16 + l16
  const float* brow = bias + ((size_t)(b * NH + h) * NS + s0 + rw * 32) * NS + pair * 32 + l16;

  // stage K/V tile 0 (all 64 keys, cooperative across the 4 waves)
#pragma unroll
  for (int i = 0; i < 4; i++)
    glds16(Kbase + (size_t)(wave * 16 + l16) * NCQK + (i * 4 + quad) * 8,
           &Ks[(wave * 16 + i * 4) * 128]);
#pragma unroll
  for (int i = 0; i < 6; i++) {
    int g = wave * 6 + i, cb = g >> 1, kh = g & 1;
    glds16(Vbase + (size_t)(cb * 16 + l16) * NS + (kh * 4 + quad) * 8,
           &Vs[(cb * 8 + kh * 4) * 128]);
  }
  // bias tile 0 -> regs: breg[(mf*2+nb)*4+r]
  float breg[16];
#pragma unroll
  for (int mf = 0; mf < 2; mf++)
#pragma unroll
    for (int nb = 0; nb < 2; nb++)
#pragma unroll
      for (int r = 0; r < 4; r++)
        breg[(mf * 2 + nb) * 4 + r] = brow[(size_t)(mf * 16 + quad * 4 + r) * NS + nb * 16];
  __syncthreads();

  f32x4 oacc[2][12] = {};
  float lsum[8] = {};  // [mf*4+r], this wave's key-half partial

  const int pwb = wave * 1024;  // per-wave Ps region (u16)

  for (int kt = 0; kt < NS / 64; kt++) {
    // QK^T: 32 rows x 32 keys (this pair's half), kf shared by both m-frags
    f32x4 sacc[2][2] = {};
    __builtin_amdgcn_s_setprio(1);
#pragma unroll
    for (int kk = 0; kk < 4; kk++)
#pragma unroll
      for (int nb = 0; nb < 2; nb++) {
        bf16x8 kf = *(const bf16x8*)&Ks[(((pair * 2 + nb) * 16 + kk * 4 + quad) * 16 + l16) * 8];
        sacc[0][nb] = mfma16(qa[0][kk], kf, sacc[0][nb]);
        sacc[1][nb] = mfma16(qa[1][kk], kf, sacc[1][nb]);
      }
    __builtin_amdgcn_s_setprio(0);

    // softcap + exp -> Ps (bf16); consumes breg
    // Ps layout per (wave, mf): element (row, k) at (k>>3)*128 + row*8 + (k&7),
    // k in [0,32) = this pair's keys, row in [0,16).
#pragma unroll
    for (int mf = 0; mf < 2; mf++)
#pragma unroll
      for (int nb = 0; nb < 2; nb++) {
        const int xk = nb * 16 + l16;  // key within this pair's 32
#pragma unroll
        for (int r = 0; r < 4; r++) {
          float a = fmaf(sacc[mf][nb][r], C1, breg[(mf * 2 + nb) * 4 + r] * C2);
          float e2;
          asm("v_exp_f32 %0, %1" : "=v"(e2) : "v"(a));
          float u = __builtin_amdgcn_rcpf(e2 + 1.f);
          float a2 = fmaf(u, C3, C4);
          float p;
          asm("v_exp_f32 %0, %1" : "=v"(p) : "v"(a2));
          unsigned pk;
          asm("v_cvt_pk_bf16_f32 %0, %1, %2" : "=v"(pk) : "v"(p), "v"(p));
          lsum[mf * 4 + r] += __builtin_bit_cast(float, pk << 16);
          Ps[pwb + mf * 512 + (xk >> 3) * 128 + (quad * 4 + r) * 8 + (xk & 7)] = (u16)pk;
        }
      }

    // prefetch next bias tile: PV MFMAs cover the latency
    if (kt + 1 < NS / 64) {
      const int key0 = (kt + 1) * 64;
#pragma unroll
      for (int mf = 0; mf < 2; mf++)
#pragma unroll
        for (int nb = 0; nb < 2; nb++)
#pragma unroll
          for (int r = 0; r < 4; r++)
            breg[(mf * 2 + nb) * 4 + r] = brow[(size_t)(mf * 16 + quad * 4 + r) * NS + key0 + nb * 16];
    }

    // PV over this pair's 32 keys; vf shared by both m-frags
    __builtin_amdgcn_s_setprio(1);
    bf16x8 pa0 = *(const bf16x8*)&Ps[pwb + quad * 128 + l16 * 8];
    bf16x8 pa1 = *(const bf16x8*)&Ps[pwb + 512 + quad * 128 + l16 * 8];
#pragma unroll
    for (int nb = 0; nb < 12; nb++) {
      bf16x8 vf = *(const bf16x8*)&Vs[((nb * 8 + pair * 4 + quad) * 16 + l16) * 8];
      oacc[0][nb] = mfma16(pa0, vf, oacc[0][nb]);
      oacc[1][nb] = mfma16(pa1, vf, oacc[1][nb]);
    }
    __builtin_amdgcn_s_setprio(0);

    // stage next K/V tile
    if (kt + 1 < NS / 64) {
      const int key0 = (kt + 1) * 64;
      __syncthreads();
#pragma unroll
      for (int i = 0; i < 4; i++)
        glds16(Kbase + (size_t)(key0 + wave * 16 + l16) * NCQK + (i * 4 + quad) * 8,
               &Ks[(wave * 16 + i * 4) * 128]);
#pragma unroll
      for (int i = 0; i < 6; i++) {
        int g = wave * 6 + i, cb = g >> 1, kh = g & 1;
        glds16(Vbase + (size_t)(cb * 16 + l16) * NS + key0 + (kh * 4 + quad) * 8,
               &Vs[(cb * 8 + kh * 4) * 128]);
      }
      __syncthreads();
    }
  }

  // reduce lsum across the 16 key-lanes
#pragma unroll
  for (int i = 0; i < 8; i++)
    for (int o = 1; o < 16; o <<= 1) lsum[i] += __shfl_xor(lsum[i], o);

  // combine the two key-half partials: pair1 -> smem (f32), pair0 adds + writes Y
  __syncthreads();
  float* smemF = (float*)smem;  // 64 rows x 192 cols = 12288 f32 = 48KB exactly
  if (pair == 1) {
#pragma unroll
    for (int mf = 0; mf < 2; mf++) {
#pragma unroll
      for (int r = 0; r < 4; r++) {
        const int row = rw * 32 + mf * 16 + quad * 4 + r;
#pragma unroll
        for (int nb = 0; nb < 12; nb++)
          smemF[row * 192 + nb * 16 + l16] = oacc[mf][nb][r];
        if (l16 == 0) lbuf[row] = lsum[mf * 4 + r];
      }
    }
  }
  __syncthreads();
  if (pair == 0) {
#pragma unroll
    for (int mf = 0; mf < 2; mf++)
#pragma unroll
      for (int r = 0; r < 4; r++) {
        const int row = rw * 32 + mf * 16 + quad * 4 + r;
        const float inv = 1.f / (lsum[mf * 4 + r] + lbuf[row]);
        u16* yr = Y + (size_t)(b * NS + s0 + row) * ND + h * NCV;
#pragma unroll
        for (int nb = 0; nb < 12; nb++)
          yr[nb * 16 + l16] = f2bf((oacc[mf][nb][r] + smemF[row * 192 + nb * 16 + l16]) * inv);
      }
  }
}

// ---------------- +bo, rmsnorm, write fp32 out ----------------
__global__ void final_k(const u16* __restrict__ yo, const float* __restrict__ bo,
                        const float* __restrict__ scale, float* __restrict__ out) {
  __shared__ float sbuf[4];
  const int row = blockIdx.x, tid = threadIdx.x;
  const u16* yr = yo + (size_t)row * ND;
  float v[6]; float ss = 0.f;
  for (int i = 0; i < 6; i++) {
    int c = tid + i * 256;
    v[i] = bf2f(yr[c]) + bo[c];
    ss += v[i] * v[i];
  }
  for (int o = 32; o; o >>= 1) ss += __shfl_xor(ss, o);
  if ((tid & 63) == 0) sbuf[tid >> 6] = ss;
  __syncthreads();
  ss = sbuf[0] + sbuf[1] + sbuf[2] + sbuf[3];
  const float inv = rsqrtf(ss * (1.f / ND) + 1e-6f);
  float* orow = out + (size_t)row * ND;
  for (int i = 0; i < 6; i++) {
    int c = tid + i * 256;
    orow[c] = v[i] * inv * scale[c];
  }
}

extern "C" void kernel_launch(void* const* d_in, const int* in_sizes, int n_in,
                              void* d_out, int out_size, void* d_ws, size_t ws_size,
                              hipStream_t stream) {
  const float* x    = (const float*)d_in[0];
  const float* bias = (const float*)d_in[1];
  const float* rin  = (const float*)d_in[2];
  const float* wq   = (const float*)d_in[3];
  const float* wk   = (const float*)d_in[4];
  const float* wv   = (const float*)d_in[5];
  const float* qsc  = (const float*)d_in[6];
  const float* qof  = (const float*)d_in[7];
  const float* ksc  = (const float*)d_in[8];
  const float* kof  = (const float*)d_in[9];
  const float* vsc  = (const float*)d_in[10];
  const float* vof  = (const float*)d_in[11];
  const float* wo   = (const float*)d_in[12];
  const float* bo   = (const float*)d_in[13];
  const float* rout = (const float*)d_in[14];

  char* ws = (char*)d_ws;
  size_t off = 0;
  auto alloc = [&](size_t bytes) -> void* {
    void* p = ws + off;
    off += (bytes + 255) & ~(size_t)255;
    return p;
  };
  u16*   h    = (u16*)alloc((size_t)NBS * ND * 2);
  u16*   wtq  = (u16*)alloc((size_t)NPAD * ND * 2);
  u16*   wto  = (u16*)alloc((size_t)ND * ND * 2);
  float* qkv  = (float*)alloc((size_t)NBS * NPAD * 4);
  u16*   Qb   = (u16*)alloc((size_t)NBS * NH * NCQK * 2);
  u16*   Kb   = (u16*)alloc((size_t)NBS * NCQK * 2);
  u16*   Vtb  = (u16*)alloc((size_t)NB * NCV * NS * 2);
  u16*   Ybf  = (u16*)alloc((size_t)NBS * ND * 2);
  u16*   Yob  = (u16*)alloc((size_t)NBS * ND * 2);

  transpose_k<<<dim3(16, 24), 256, 0, stream>>>(wq, wtq, ND, 1024);
  transpose_k<<<dim3(2, 24), 256, 0, stream>>>(wk, wtq + (size_t)1024 * ND, ND, 128);
  transpose_k<<<dim3(3, 24), 256, 0, stream>>>(wv, wtq + (size_t)1152 * ND, ND, 192);
  transpose_k<<<dim3(24, 24), 256, 0, stream>>>(wo, wto, ND, ND);
  rmsnorm_in_k<<<NBS, 256, 0, stream>>>(x, rin, h);
  gemm_nt<true><<<dim3(NPAD / 128, NBS / 128), 256, 0, stream>>>(h, wtq, qkv, nullptr, NBS, NPAD, ND);
  ln_rope_k<<<NBS, 256, 0, stream>>>(qkv, qsc, qof, ksc, kof, vsc, vof, Qb, Kb, Vtb);
  attn_k<<<dim3(NS / 64, NH, NB), 256, 0, stream>>>(Qb, Kb, Vtb, bias, Ybf);
  gemm_nt<false><<<dim3(ND / 128, NBS / 128), 256, 0, stream>>>(Ybf, wto, nullptr, Yob, NBS, ND, ND);
  final_k<<<NBS, 256, 0, stream>>>(Yob, bo, rout, (float*)d_out);
}

// Round 5
// 583.601 us; speedup vs baseline: 1.0708x; 1.0040x over previous
//
#include <hip/hip_runtime.h>
#include <hip/hip_bf16.h>

typedef unsigned short u16;
typedef short bf16x8 __attribute__((ext_vector_type(8)));
typedef float f32x4 __attribute__((ext_vector_type(4)));

#define NB 2
#define NS 2048
#define ND 1536
#define NH 8
#define NCQK 128
#define NCV 192
#define NBS 4096
#define NPAD 1408

__device__ __forceinline__ float bf2f(u16 u) {
  unsigned v = ((unsigned)u) << 16;
  return __builtin_bit_cast(float, v);
}
__device__ __forceinline__ u16 f2bf(float f) {
  unsigned u = __builtin_bit_cast(unsigned, f);
  u += 0x7fffu + ((u >> 16) & 1u);
  return (u16)(u >> 16);
}
__device__ __forceinline__ void glds16(const u16* g, u16* l) {
  __builtin_amdgcn_global_load_lds(
      (const __attribute__((address_space(1))) void*)g,
      (__attribute__((address_space(3))) void*)l, 16, 0, 0);
}
__device__ __forceinline__ f32x4 mfma16(bf16x8 a, bf16x8 b, f32x4 c) {
  return __builtin_amdgcn_mfma_f32_16x16x32_bf16(a, b, c, 0, 0, 0);
}

// ---------------- transpose+cast: out[n][k] = bf16(in[k][n]), in fp32 [K][N] ----------------
__global__ void transpose_k(const float* __restrict__ in, u16* __restrict__ out,
                            int K, int N) {
  __shared__ float t[64][65];
  const int n0 = blockIdx.x * 64, k0 = blockIdx.y * 64;
  const int tid = threadIdx.x;
  const int rl = tid >> 4, cl = (tid & 15) * 4;
  for (int p = 0; p < 4; p++) {
    int k = rl + p * 16;
    float4 v = *(const float4*)(in + (size_t)(k0 + k) * N + n0 + cl);
    t[k][cl] = v.x; t[k][cl + 1] = v.y; t[k][cl + 2] = v.z; t[k][cl + 3] = v.w;
  }
  __syncthreads();
  const int rn = tid >> 3, ck = (tid & 7) * 8;
  for (int p = 0; p < 2; p++) {
    int n = rn + p * 32;
    u16 tmp[8];
    for (int j = 0; j < 8; j++) tmp[j] = f2bf(t[ck + j][n]);
    *(uint4*)(out + (size_t)(n0 + n) * K + k0 + ck) = *(uint4*)tmp;
  }
}

// ---------------- rmsnorm of x (fp32) -> h (bf16) ----------------
__global__ void rmsnorm_in_k(const float* __restrict__ x, const float* __restrict__ scale,
                             u16* __restrict__ h) {
  __shared__ float sbuf[4];
  const int row = blockIdx.x, tid = threadIdx.x;
  const float* xr = x + (size_t)row * ND;
  float v[6]; float ss = 0.f;
  for (int i = 0; i < 6; i++) { v[i] = xr[tid + i * 256]; ss += v[i] * v[i]; }
  for (int o = 32; o; o >>= 1) ss += __shfl_xor(ss, o);
  if ((tid & 63) == 0) sbuf[tid >> 6] = ss;
  __syncthreads();
  ss = sbuf[0] + sbuf[1] + sbuf[2] + sbuf[3];
  const float inv = rsqrtf(ss * (1.f / ND) + 1e-6f);
  u16* hr = h + (size_t)row * ND;
  for (int i = 0; i < 6; i++) {
    int c = tid + i * 256;
    hr[c] = f2bf(v[i] * inv * scale[c]);
  }
}

// ---------------- C[M,N] = A[M,K]bf16 @ Bt[N,K]bf16^T ; fp32 or bf16 out ----------------
// Double-buffered 2-phase K-loop: stage(t+1) issued BEFORE compute(t); loads fly
// under the 32-MFMA phase; ONE barrier per K-step (was stage->drain->2 barriers).
template <bool F32OUT>
__global__ __launch_bounds__(256, 2)
void gemm_nt(const u16* __restrict__ A, const u16* __restrict__ Bt,
             float* __restrict__ Cf, u16* __restrict__ Cb, int M, int N, int K) {
  __shared__ __align__(16) u16 As[2][64 * 128];
  __shared__ __align__(16) u16 Bs[2][64 * 128];
  const int tid = threadIdx.x;
  const int wave = tid >> 6, lane = tid & 63, quad = lane >> 4, l16 = lane & 15;
  const int m0 = blockIdx.y * 128, n0 = blockIdx.x * 128;
  const int mrb = (wave & 1) * 4, nrb = (wave >> 1) * 4;
  f32x4 acc[4][4] = {};

  auto stage = [&](int buf, int k0) {
#pragma unroll
    for (int i = 0; i < 4; i++) {
      int g = wave * 4 + i;
      int rb = g >> 1, kh = g & 1;
      int row = rb * 16 + l16, kc = kh * 4 + quad;
      glds16(A + (size_t)(m0 + row) * K + k0 + kc * 8, &As[buf][(rb * 8 + kh * 4) * 128]);
      glds16(Bt + (size_t)(n0 + row) * K + k0 + kc * 8, &Bs[buf][(rb * 8 + kh * 4) * 128]);
    }
  };

  const int nt = K >> 6;
  stage(0, 0);
  __syncthreads();
  for (int t = 0; t < nt; t++) {
    const int cur = t & 1;
    if (t + 1 < nt) stage(cur ^ 1, (t + 1) * 64);
#pragma unroll
    for (int kk = 0; kk < 2; kk++) {
      bf16x8 af[4], bfr[4];
#pragma unroll
      for (int f = 0; f < 4; f++)
        af[f] = *(const bf16x8*)&As[cur][(((mrb + f) * 8 + kk * 4 + quad) * 16 + l16) * 8];
#pragma unroll
      for (int f = 0; f < 4; f++)
        bfr[f] = *(const bf16x8*)&Bs[cur][(((nrb + f) * 8 + kk * 4 + quad) * 16 + l16) * 8];
#pragma unroll
      for (int mf = 0; mf < 4; mf++)
#pragma unroll
        for (int nf = 0; nf < 4; nf++)
          acc[mf][nf] = mfma16(af[mf], bfr[nf], acc[mf][nf]);
    }
    __syncthreads();  // drains next-tile loads (they overlapped compute) + guards buf reuse
  }

  for (int mf = 0; mf < 4; mf++)
    for (int nf = 0; nf < 4; nf++)
      for (int r = 0; r < 4; r++) {
        int m = m0 + (wave & 1) * 64 + mf * 16 + quad * 4 + r;
        int n = n0 + (wave >> 1) * 64 + nf * 16 + l16;
        if (F32OUT) Cf[(size_t)m * N + n] = acc[mf][nf][r];
        else        Cb[(size_t)m * N + n] = f2bf(acc[mf][nf][r]);
      }
}

// ---------------- layernorm + rope on qkv rows (fp32 in, bf16 out) ----------------
__global__ void ln_rope_k(const float* __restrict__ qkv,
                          const float* __restrict__ qs, const float* __restrict__ qo,
                          const float* __restrict__ ks, const float* __restrict__ ko,
                          const float* __restrict__ vs, const float* __restrict__ vo,
                          u16* __restrict__ Qg, u16* __restrict__ Kg, u16* __restrict__ Vg) {
  const int row = blockIdx.x;
  const int b = row >> 11, s = row & (NS - 1);
  const int wave = threadIdx.x >> 6, lane = threadIdx.x & 63;
  const float* base = qkv + (size_t)row * NPAD;
  const float gsp = __expf(logf(8129.f) * ((float)lane * (1.f / 63.f)));
  const float invf = 1.f / ((float)lane + gsp);
  float sn, cs;
  sincosf((float)s * invf, &sn, &cs);

  for (int hh = 0; hh < 2; hh++) {
    const int h = wave * 2 + hh;
    const float* p = base + h * NCQK;
    float x0 = p[lane * 2], x1 = p[lane * 2 + 1];
    float s1 = x0 + x1, s2 = x0 * x0 + x1 * x1;
    for (int o = 32; o; o >>= 1) { s1 += __shfl_xor(s1, o); s2 += __shfl_xor(s2, o); }
    float mean = s1 * (1.f / NCQK);
    float inv = rsqrtf(s2 * (1.f / NCQK) - mean * mean + 1e-5f);
    float y0 = (x0 - mean) * inv * qs[lane * 2] + qo[lane * 2];
    float y1 = (x1 - mean) * inv * qs[lane * 2 + 1] + qo[lane * 2 + 1];
    u16* dst = Qg + (size_t)row * (NH * NCQK) + h * NCQK + lane * 2;
    dst[0] = f2bf(y0 * cs - y1 * sn);
    dst[1] = f2bf(y1 * cs + y0 * sn);
  }
  if (wave == 0) {
    const float* p = base + NH * NCQK;
    float x0 = p[lane * 2], x1 = p[lane * 2 + 1];
    float s1 = x0 + x1, s2 = x0 * x0 + x1 * x1;
    for (int o = 32; o; o >>= 1) { s1 += __shfl_xor(s1, o); s2 += __shfl_xor(s2, o); }
    float mean = s1 * (1.f / NCQK);
    float inv = rsqrtf(s2 * (1.f / NCQK) - mean * mean + 1e-5f);
    float y0 = (x0 - mean) * inv * ks[lane * 2] + ko[lane * 2];
    float y1 = (x1 - mean) * inv * ks[lane * 2 + 1] + ko[lane * 2 + 1];
    u16* dst = Kg + (size_t)row * NCQK + lane * 2;
    dst[0] = f2bf(y0 * cs - y1 * sn);
    dst[1] = f2bf(y1 * cs + y0 * sn);
  }
  if (wave == 1) {
    const float* p = base + NH * NCQK + NCQK;
    float x[3]; float s1 = 0.f, s2 = 0.f;
    for (int i = 0; i < 3; i++) { x[i] = p[lane + i * 64]; s1 += x[i]; s2 += x[i] * x[i]; }
    for (int o = 32; o; o >>= 1) { s1 += __shfl_xor(s1, o); s2 += __shfl_xor(s2, o); }
    float mean = s1 * (1.f / NCV);
    float inv = rsqrtf(s2 * (1.f / NCV) - mean * mean + 1e-5f);
    for (int i = 0; i < 3; i++) {
      int c = lane + i * 64;
      float y = (x[i] - mean) * inv * vs[c] + vo[c];
      Vg[(size_t)(b * NCV + c) * NS + s] = f2bf(y);
    }
  }
}

// ---------------- fused MQA attention ----------------
// 64 q-rows x 64-key tiles; key-split pairs, 32 rows/wave (round-4 structure).
// NEW: split-barrier staging — K-stage(t+1) issued after sync#1 (overlaps PV),
// V-stage(t+1) issued after sync#2 (overlaps next QK). Zero extra LDS; no
// immediate vmcnt drain after issue.
__global__ __launch_bounds__(256, 2)
void attn_k(const u16* __restrict__ Qg, const u16* __restrict__ Kg,
            const u16* __restrict__ Vg, const float* __restrict__ bias,
            u16* __restrict__ Y) {
  __shared__ __align__(16) u16 smem[24576];  // Ks[0,8192) Vs[8192,20480) Ps[20480,24576)
  __shared__ float lbuf[64];
  u16* Ks = smem;
  u16* Vs = smem + 8192;
  u16* Ps = smem + 20480;
  const int tid = threadIdx.x;
  const int wave = tid >> 6, lane = tid & 63, quad = lane >> 4, l16 = lane & 15;
  const int pair = wave >> 1, rw = wave & 1;   // pair: key half; rw: row half
  const int s0 = blockIdx.x * 64;
  const int h = blockIdx.y, b = blockIdx.z;

  // P = exp(5*tanh(sv/5)), sv = sacc*0.08838835 + bias.
  // e2 = 2^(sacc*C1 + bias*C2) = e^{0.4 sv}; P = 2^(C4 + C3/(e2+1)) = e^{5 - 10/(e2+1)}
  const float C1 = 0.0510069742f;
  const float C2 = 0.5770780163f;
  const float C3 = -14.4269504089f;
  const float C4 = 7.2134752044f;

  // Q: 32 rows/wave, 2 m-frags, straight to registers
  bf16x8 qa[2][4];
#pragma unroll
  for (int mf = 0; mf < 2; mf++) {
    const u16* qr = Qg + ((size_t)((b * NS + s0 + rw * 32 + mf * 16 + l16) * NH + h)) * NCQK;
#pragma unroll
    for (int kk = 0; kk < 4; kk++)
      qa[mf][kk] = *(const bf16x8*)(qr + (kk * 4 + quad) * 8);
  }

  const u16* Kbase = Kg + (size_t)(b * NS) * NCQK;
  const u16* Vbase = Vg + (size_t)(b * NCV) * NS;
  const float* brow = bias + ((size_t)(b * NH + h) * NS + s0 + rw * 32) * NS + pair * 32 + l16;

  auto stageK = [&](int key0) {
#pragma unroll
    for (int i = 0; i < 4; i++)
      glds16(Kbase + (size_t)(key0 + wave * 16 + l16) * NCQK + (i * 4 + quad) * 8,
             &Ks[(wave * 16 + i * 4) * 128]);
  };
  auto stageV = [&](int key0) {
#pragma unroll
    for (int i = 0; i < 6; i++) {
      int g = wave * 6 + i, cb = g >> 1, kh = g & 1;
      glds16(Vbase + (size_t)(cb * 16 + l16) * NS + key0 + (kh * 4 + quad) * 8,
             &Vs[(cb * 8 + kh * 4) * 128]);
    }
  };

  float breg[16];
  auto loadB = [&](int key0) {
#pragma unroll
    for (int mf = 0; mf < 2; mf++)
#pragma unroll
      for (int nb = 0; nb < 2; nb++)
#pragma unroll
        for (int r = 0; r < 4; r++)
          breg[(mf * 2 + nb) * 4 + r] = brow[(size_t)(mf * 16 + quad * 4 + r) * NS + key0 + nb * 16];
  };

  stageK(0);
  stageV(0);
  loadB(0);
  __syncthreads();

  f32x4 oacc[2][12] = {};
  float lsum[8] = {};

  const int pwb = wave * 1024;  // per-wave Ps region (u16)
  const int NT = NS / 64;

  for (int kt = 0; kt < NT; kt++) {
    // QK^T: 32 rows x 32 keys (this pair's half), kf shared by both m-frags
    f32x4 sacc[2][2] = {};
    __builtin_amdgcn_s_setprio(1);
#pragma unroll
    for (int kk = 0; kk < 4; kk++)
#pragma unroll
      for (int nb = 0; nb < 2; nb++) {
        bf16x8 kf = *(const bf16x8*)&Ks[(((pair * 2 + nb) * 16 + kk * 4 + quad) * 16 + l16) * 8];
        sacc[0][nb] = mfma16(qa[0][kk], kf, sacc[0][nb]);
        sacc[1][nb] = mfma16(qa[1][kk], kf, sacc[1][nb]);
      }
    __builtin_amdgcn_s_setprio(0);

    // softcap + exp -> Ps (bf16); consumes breg
#pragma unroll
    for (int mf = 0; mf < 2; mf++)
#pragma unroll
      for (int nb = 0; nb < 2; nb++) {
        const int xk = nb * 16 + l16;
#pragma unroll
        for (int r = 0; r < 4; r++) {
          float a = fmaf(sacc[mf][nb][r], C1, breg[(mf * 2 + nb) * 4 + r] * C2);
          float e2;
          asm("v_exp_f32 %0, %1" : "=v"(e2) : "v"(a));
          float u = __builtin_amdgcn_rcpf(e2 + 1.f);
          float a2 = fmaf(u, C3, C4);
          float p;
          asm("v_exp_f32 %0, %1" : "=v"(p) : "v"(a2));
          unsigned pk;
          asm("v_cvt_pk_bf16_f32 %0, %1, %2" : "=v"(pk) : "v"(p), "v"(p));
          lsum[mf * 4 + r] += __builtin_bit_cast(float, pk << 16);
          Ps[pwb + mf * 512 + (xk >> 3) * 128 + (quad * 4 + r) * 8 + (xk & 7)] = (u16)pk;
        }
      }

    // sync#1: all waves done reading Ks; drains V(kt) loads issued at end of kt-1
    __syncthreads();

    // issue K(t+1) + bias(t+1): they fly under PV
    if (kt + 1 < NT) {
      stageK((kt + 1) * 64);
      loadB((kt + 1) * 64);
    }

    // PV over this pair's 32 keys; vf shared by both m-frags
    __builtin_amdgcn_s_setprio(1);
    bf16x8 pa0 = *(const bf16x8*)&Ps[pwb + quad * 128 + l16 * 8];
    bf16x8 pa1 = *(const bf16x8*)&Ps[pwb + 512 + quad * 128 + l16 * 8];
#pragma unroll
    for (int nb = 0; nb < 12; nb++) {
      bf16x8 vf = *(const bf16x8*)&Vs[((nb * 8 + pair * 4 + quad) * 16 + l16) * 8];
      oacc[0][nb] = mfma16(pa0, vf, oacc[0][nb]);
      oacc[1][nb] = mfma16(pa1, vf, oacc[1][nb]);
    }
    __builtin_amdgcn_s_setprio(0);

    // sync#2: all waves done reading Vs; drains K(t+1) loads (they had PV to land)
    __syncthreads();

    // issue V(t+1): flies under next QK
    if (kt + 1 < NT) stageV((kt + 1) * 64);
  }

  // reduce lsum across the 16 key-lanes
#pragma unroll
  for (int i = 0; i < 8; i++)
    for (int o = 1; o < 16; o <<= 1) lsum[i] += __shfl_xor(lsum[i], o);

  // combine the two key-half partials: pair1 -> smem (f32), pair0 adds + writes Y
  __syncthreads();
  float* smemF = (float*)smem;  // 64 rows x 192 cols = 12288 f32 = 48KB exactly
  if (pair == 1) {
#pragma unroll
    for (int mf = 0; mf < 2; mf++) {
#pragma unroll
      for (int r = 0; r < 4; r++) {
        const int row = rw * 32 + mf * 16 + quad * 4 + r;
#pragma unroll
        for (int nb = 0; nb < 12; nb++)
          smemF[row * 192 + nb * 16 + l16] = oacc[mf][nb][r];
        if (l16 == 0) lbuf[row] = lsum[mf * 4 + r];
      }
    }
  }
  __syncthreads();
  if (pair == 0) {
#pragma unroll
    for (int mf = 0; mf < 2; mf++)
#pragma unroll
      for (int r = 0; r < 4; r++) {
        const int row = rw * 32 + mf * 16 + quad * 4 + r;
        const float inv = 1.f / (lsum[mf * 4 + r] + lbuf[row]);
        u16* yr = Y + (size_t)(b * NS + s0 + row) * ND + h * NCV;
#pragma unroll
        for (int nb = 0; nb < 12; nb++)
          yr[nb * 16 + l16] = f2bf((oacc[mf][nb][r] + smemF[row * 192 + nb * 16 + l16]) * inv);
      }
  }
}

// ---------------- +bo, rmsnorm, write fp32 out ----------------
__global__ void final_k(const u16* __restrict__ yo, const float* __restrict__ bo,
                        const float* __restrict__ scale, float* __restrict__ out) {
  __shared__ float sbuf[4];
  const int row = blockIdx.x, tid = threadIdx.x;
  const u16* yr = yo + (size_t)row * ND;
  float v[6]; float ss = 0.f;
  for (int i = 0; i < 6; i++) {
    int c = tid + i * 256;
    v[i] = bf2f(yr[c]) + bo[c];
    ss += v[i] * v[i];
  }
  for (int o = 32; o; o >>= 1) ss += __shfl_xor(ss, o);
  if ((tid & 63) == 0) sbuf[tid >> 6] = ss;
  __syncthreads();
  ss = sbuf[0] + sbuf[1] + sbuf[2] + sbuf[3];
  const float inv = rsqrtf(ss * (1.f / ND) + 1e-6f);
  float* orow = out + (size_t)row * ND;
  for (int i = 0; i < 6; i++) {
    int c = tid + i * 256;
    orow[c] = v[i] * inv * scale[c];
  }
}

extern "C" void kernel_launch(void* const* d_in, const int* in_sizes, int n_in,
                              void* d_out, int out_size, void* d_ws, size_t ws_size,
                              hipStream_t stream) {
  const float* x    = (const float*)d_in[0];
  const float* bias = (const float*)d_in[1];
  const float* rin  = (const float*)d_in[2];
  const float* wq   = (const float*)d_in[3];
  const float* wk   = (const float*)d_in[4];
  const float* wv   = (const float*)d_in[5];
  const float* qsc  = (const float*)d_in[6];
  const float* qof  = (const float*)d_in[7];
  const float* ksc  = (const float*)d_in[8];
  const float* kof  = (const float*)d_in[9];
  const float* vsc  = (const float*)d_in[10];
  const float* vof  = (const float*)d_in[11];
  const float* wo   = (const float*)d_in[12];
  const float* bo   = (const float*)d_in[13];
  const float* rout = (const float*)d_in[14];

  char* ws = (char*)d_ws;
  size_t off = 0;
  auto alloc = [&](size_t bytes) -> void* {
    void* p = ws + off;
    off += (bytes + 255) & ~(size_t)255;
    return p;
  };
  u16*   h    = (u16*)alloc((size_t)NBS * ND * 2);
  u16*   wtq  = (u16*)alloc((size_t)NPAD * ND * 2);
  u16*   wto  = (u16*)alloc((size_t)ND * ND * 2);
  float* qkv  = (float*)alloc((size_t)NBS * NPAD * 4);
  u16*   Qb   = (u16*)alloc((size_t)NBS * NH * NCQK * 2);
  u16*   Kb   = (u16*)alloc((size_t)NBS * NCQK * 2);
  u16*   Vtb  = (u16*)alloc((size_t)NB * NCV * NS * 2);
  u16*   Ybf  = (u16*)alloc((size_t)NBS * ND * 2);
  u16*   Yob  = (u16*)alloc((size_t)NBS * ND * 2);

  transpose_k<<<dim3(16, 24), 256, 0, stream>>>(wq, wtq, ND, 1024);
  transpose_k<<<dim3(2, 24), 256, 0, stream>>>(wk, wtq + (size_t)1024 * ND, ND, 128);
  transpose_k<<<dim3(3, 24), 256, 0, stream>>>(wv, wtq + (size_t)1152 * ND, ND, 192);
  transpose_k<<<dim3(24, 24), 256, 0, stream>>>(wo, wto, ND, ND);
  rmsnorm_in_k<<<NBS, 256, 0, stream>>>(x, rin, h);
  gemm_nt<true><<<dim3(NPAD / 128, NBS / 128), 256, 0, stream>>>(h, wtq, qkv, nullptr, NBS, NPAD, ND);
  ln_rope_k<<<NBS, 256, 0, stream>>>(qkv, qsc, qof, ksc, kof, vsc, vof, Qb, Kb, Vtb);
  attn_k<<<dim3(NS / 64, NH, NB), 256, 0, stream>>>(Qb, Kb, Vtb, bias, Ybf);
  gemm_nt<false><<<dim3(ND / 128, NBS / 128), 256, 0, stream>>>(Ybf, wto, nullptr, Yob, NBS, ND, ND);
  final_k<<<NBS, 256, 0, stream>>>(Yob, bo, rout, (float*)d_out);
}